// Round 8
// baseline (1122.516 us; speedup 1.0000x reference)
//
#include <hip/hip_runtime.h>

// ---------------------------------------------------------------------------
// Two-layer tanh RNN — round 10: MFMA compute core on the R7 exchange skeleton.
// B=64, T=512, H=512, I=128, W_OUT=32. fp32 in/out, f16 internal, fp32 acc.
//
// Exchange (VERBATIM from R7 champion): 64 clusters = {layer} x {batch-pair},
// 4 sibling WGs x 1024 thr, 1 WG/CU; tagged {tag32|f16pair} atoms, RELAXED
// agent scope; hb0 DRING=256 + consumer-progress throttle; hb1 4-ring; epoch
// tags; h0 prefetch pipeline (L1 w<8); remote prefetch at bottom of step;
// FC epilogue in L1 s==0.
//
// Compute core (NEW): h state in flat LDS hflat[parity][batch][pair] (dwords).
// Stage roles write 1 dword/lane (as R7). Dots = MFMA 16x16x32 f16:
//   wave = (k-chunk kc, row-group rg). A-frags = weights, persistent in VGPRs
//   (64 regs). B-frags: KT distributed ds_read_b128 per wave, SHARED across
//   RT row-tiles (this is the 4x LDS-read cut vs per-lane-private dots).
//   B cols 0,1 = batches; cols 2-15 replicate col0/1 data (ignored in C).
//   C partials (cols<2 masked) -> psum[parity][kc][batch][row]; reduce lanes
//   sum KC partials + bias + noise, tanh, pack, post, and write OWN pairs
//   into hflat[p^1] (feeds next step's dots directly — no LDS hown, no
//   special own-chunk path).
// L0: K=640 (x 128 + h0 512) = 4 kc x 5 kt; 4 rg x 2 row-tiles. NPAIR=320.
// L1: K=1024 (h0+h1)        = 8 kc x 4 kt; 2 rg x 4 row-tiles. NPAIR=512.
// Barriers: 2 lgkm-only per step (stage->dots, dots->reduce). hflat and psum
// double-buffered by parity; reduce(t) writes hflat[p^1] sealed by bar_s(t+1).
// Fragment layouts = R5-verified (A/B share k-formula => permutation cancels;
// C: col=lane&15, row=4*(lane>>4)+reg).
// ---------------------------------------------------------------------------

#define T_STEPS 512
#define NBATCH  64
#define DRING   256
#define THR_LEAD 192

typedef _Float16 half2v __attribute__((ext_vector_type(2)));
typedef _Float16 f16x8  __attribute__((ext_vector_type(8)));
typedef float    f32x4  __attribute__((ext_vector_type(4)));

__device__ __forceinline__ unsigned pack2(float a, float b) {
    _Float16 fa = (_Float16)a, fb = (_Float16)b;
    unsigned short ua = __builtin_bit_cast(unsigned short, fa);
    unsigned short ub = __builtin_bit_cast(unsigned short, fb);
    return (unsigned)ua | ((unsigned)ub << 16);
}

__device__ __forceinline__ float fast_tanh(float xv) {
    float e2 = __builtin_amdgcn_exp2f(xv * 2.885390082f);
    return 1.f - 2.f * __builtin_amdgcn_rcpf(e2 + 1.f);
}

__device__ __forceinline__ f32x4 mfma16(uint4 a, uint4 b, f32x4 c) {
    return __builtin_amdgcn_mfma_f32_16x16x32_f16(
        __builtin_bit_cast(f16x8, a), __builtin_bit_cast(f16x8, b), c, 0, 0, 0);
}

// Workgroup barrier with LDS-only drain (posts/prefetches stay in flight).
__device__ __forceinline__ void bar_lgkm() {
    asm volatile("s_waitcnt lgkmcnt(0)\n\ts_barrier" ::: "memory");
}

__device__ __forceinline__ unsigned poll1(unsigned long long* p, unsigned tag,
                                          long& budget) {
    unsigned long long v = __hip_atomic_load(p, __ATOMIC_RELAXED, __HIP_MEMORY_SCOPE_AGENT);
    while ((unsigned)(v >> 32) != tag && budget > 0) {
        v = __hip_atomic_load(p, __ATOMIC_RELAXED, __HIP_MEMORY_SCOPE_AGENT);
        --budget;
    }
    return (unsigned)v;
}

// A-fragment weight packs: wp[((s*16 + w)*16 + f)*64 + lane] (uint4).
// L0: wave w: kc=w>>2, rg=w&3; frag f = j*5+ktl (j<2 row-tiles, ktl<5), f>=10 zero.
// L1: wave w: kc=w>>1, rg=w&1; frag f = j*4+ktl (j<4, ktl<4).
// Element: row r = s*128 + (rg*RT+j)*16 + (lane&15);
//          pair kp = kc*KCP + ktl*16 + (lane>>4)*4 + d  (d=0..3; k=2*kp).
// L0 pair-space: kp<64 = x, else h0 pair kp-64. L1: kp<256 = h0, else h1 kp-256.
#define NWPF (4 * 16 * 16 * 64)

__global__ void init_pack(const float* __restrict__ Wih0, const float* __restrict__ Whh0,
                          const float* __restrict__ Wih1, const float* __restrict__ Whh1,
                          uint4* __restrict__ wp0, uint4* __restrict__ wp1,
                          int* __restrict__ prog) {
    int gid = blockIdx.x * 256 + threadIdx.x;
    if (gid == 32) prog[32] = prog[32] + 1;   // epoch bump (replay-unique tags)
    if (gid < 32) prog[gid] = 0;
    if (gid < NWPF) {
        int lane = gid & 63, f = (gid >> 6) & 15, w = (gid >> 10) & 15, s = gid >> 14;
        uint4 o = make_uint4(0, 0, 0, 0);
        if (f < 10) {
            int kc = w >> 2, rg = w & 3, j = f / 5, ktl = f % 5;
            int r = s * 128 + (rg * 2 + j) * 16 + (lane & 15);
            unsigned dv[4];
#pragma unroll
            for (int d = 0; d < 4; ++d) {
                int kp = kc * 80 + ktl * 16 + ((lane >> 4) * 4) + d;
                float w0, w1;
                if (kp < 64) { w0 = Wih0[r * 128 + 2 * kp]; w1 = Wih0[r * 128 + 2 * kp + 1]; }
                else { int p0 = kp - 64;
                       w0 = Whh0[r * 512 + 2 * p0]; w1 = Whh0[r * 512 + 2 * p0 + 1]; }
                dv[d] = pack2(w0, w1);
            }
            o = make_uint4(dv[0], dv[1], dv[2], dv[3]);
        }
        wp0[gid] = o;
    } else if (gid < 2 * NWPF) {
        int idx = gid - NWPF;
        int lane = idx & 63, f = (idx >> 6) & 15, w = (idx >> 10) & 15, s = idx >> 14;
        int kc = w >> 1, rg = w & 1, j = f >> 2, ktl = f & 3;
        int r = s * 128 + (rg * 4 + j) * 16 + (lane & 15);
        unsigned dv[4];
#pragma unroll
        for (int d = 0; d < 4; ++d) {
            int kp = kc * 64 + ktl * 16 + ((lane >> 4) * 4) + d;
            float w0, w1;
            if (kp < 256) { w0 = Wih1[r * 512 + 2 * kp]; w1 = Wih1[r * 512 + 2 * kp + 1]; }
            else { int p1 = kp - 256;
                   w0 = Whh1[r * 512 + 2 * p1]; w1 = Whh1[r * 512 + 2 * p1 + 1]; }
            dv[d] = pack2(w0, w1);
        }
        wp1[idx] = make_uint4(dv[0], dv[1], dv[2], dv[3]);
    }
}

template <int LAYER>
__device__ __forceinline__ void run_layer(
    int b0, int s, int L, int pair,
    const float* __restrict__ x, const float* __restrict__ noise,
    const uint4* __restrict__ wp,
    const float* __restrict__ bih, const float* __restrict__ bhh,
    unsigned long long* __restrict__ hb0, unsigned long long* __restrict__ hb1,
    int* __restrict__ prog,
    const float* __restrict__ fcw, const float* __restrict__ fcb,
    float* __restrict__ out) {
    constexpr int KC    = (LAYER == 0) ? 4 : 8;     // k-chunks
    constexpr int KT    = (LAYER == 0) ? 5 : 4;     // k-tiles (of 32) per chunk
    constexpr int RT    = (LAYER == 0) ? 2 : 4;     // row-tiles per wave
    constexpr int NPAIR = (LAYER == 0) ? 320 : 512; // flat pair space
    constexpr int OWNB  = (LAYER == 0) ? 64 : 256;  // own-h base in pair space
    constexpr int NF    = (LAYER == 0) ? 10 : 16;   // A-frags per wave
    constexpr int KCP   = (LAYER == 0) ? 80 : 64;   // pairs per chunk

    const int w = L >> 6, lane = L & 63;
    const unsigned tagbase = ((unsigned)prog[32]) << 10;
    long budget = 2000000000L;

    // ---- persistent A-fragments ----
    uint4 wfr[NF];
#pragma unroll
    for (int f = 0; f < NF; ++f) {
        wfr[f] = wp[(size_t)(((s * 16 + w) * 16) + f) * 64 + lane];
        asm volatile("" : "+v"(wfr[f].x), "+v"(wfr[f].y), "+v"(wfr[f].z), "+v"(wfr[f].w));
    }

    __shared__ __align__(16) unsigned hflat[2][2][NPAIR];  // [parity][batch][pair]
    __shared__ __align__(16) float psum[2][KC][2][128];    // [parity][kc][batch][row]
    for (int i = L; i < 2 * 2 * NPAIR; i += 1024) ((unsigned*)hflat)[i] = 0u;  // h(-1)=0

    // reduce-role constants (lanes 0..255: bb = L>>7, row rw = L&127)
    const bool isRed = (L < 256);
    const int bbr = L >> 7, rw = L & 127;
    const int rgl = s * 128 + rw;
    float cb = 0.f, nz = 0.f;
    if (isRed) {
        cb = bih[rgl] + bhh[rgl];
        nz = noise[(((size_t)(b0 + bbr) * T_STEPS + 0) * 2 + LAYER) * 512 + rgl];
    }
    __syncthreads();

    unsigned long long pf = 0;    // L1 w<8: h0 prefetch
    unsigned long long pfR = 0;   // remote-h prefetch
    float2 xf = make_float2(0.f, 0.f);
    if constexpr (LAYER == 0) {
        if (w >= 14) {
            int j = lane & 31, bbl = lane >> 5, px = (w - 14) * 32 + j;
            xf = *(const float2*)(x + ((size_t)(b0 + bbl) * T_STEPS + 0) * 128 + 2 * px);
        }
    }

    int known = 0;
    const int colm = lane & 15, kg = lane >> 4;
    const int kcv = (LAYER == 0) ? (w >> 2) : (w >> 1);
    const int rg  = (LAYER == 0) ? (w & 3)  : (w & 1);

    for (int t = 0; t < T_STEPS; ++t) {
        const int p = t & 1;
        const bool last = (t == T_STEPS - 1);
        __builtin_amdgcn_s_setprio(1);

        // ---- STAGE: fill hflat[p] (1 dword/lane roles; R7 poll/prefetch) ----
        if constexpr (LAYER == 1) {
            if (w < 8) {                                  // h0(t) via pf pipeline
                const int j = lane & 31, bbl = lane >> 5;
                unsigned want = tagbase + (unsigned)t + 1;
                if ((unsigned)(pf >> 32) != want) {
                    __builtin_amdgcn_s_setprio(0);
                    unsigned v = poll1(&hb0[((size_t)(t & (DRING - 1)) * NBATCH + (b0 + bbl)) * 256 +
                                            (w * 32 + j)], want, budget);
                    pf = ((unsigned long long)want << 32) | v;
                    __builtin_amdgcn_s_setprio(1);
                }
                hflat[p][bbl][w * 32 + j] = (unsigned)pf;
                if (!last)
                    pf = __hip_atomic_load(&hb0[((size_t)((t + 1) & (DRING - 1)) * NBATCH +
                                                 (b0 + bbl)) * 256 + (w * 32 + j)],
                                           __ATOMIC_RELAXED, __HIP_MEMORY_SCOPE_AGENT);
            } else if (w >= 10) {                         // remote h1(t-1)
                if (t > 0) {
                    const int j = lane & 31, bbl = lane >> 5;
                    int m = (w - 10) * 32 + j;
                    int p2 = (m < s * 64) ? m : m + 64;
                    unsigned want = tagbase + (unsigned)t;
                    unsigned v;
                    if ((unsigned)(pfR >> 32) == want) v = (unsigned)pfR;
                    else {
                        __builtin_amdgcn_s_setprio(0);
                        v = poll1(&hb1[((size_t)((t - 1) & 3) * NBATCH + (b0 + bbl)) * 256 + p2],
                                  want, budget);
                        __builtin_amdgcn_s_setprio(1);
                    }
                    hflat[p][bbl][256 + p2] = v;
                }
            }
        } else {
            if (w >= 8 && w < 14) {                       // remote h0(t-1): 6 waves x 64
                if (t > 0) {
                    int idx = (w - 8) * 64 + lane;
                    int bbl = (idx >= 192) ? 1 : 0;
                    int m = idx - bbl * 192;
                    int p2 = (m < s * 64) ? m : m + 64;
                    unsigned want = tagbase + (unsigned)t;
                    unsigned v;
                    if ((unsigned)(pfR >> 32) == want) v = (unsigned)pfR;
                    else {
                        __builtin_amdgcn_s_setprio(0);
                        v = poll1(&hb0[((size_t)((t - 1) & (DRING - 1)) * NBATCH +
                                        (b0 + bbl)) * 256 + p2],
                                  want, budget);
                        __builtin_amdgcn_s_setprio(1);
                    }
                    hflat[p][bbl][64 + p2] = v;
                }
            } else if (w >= 14) {                         // x(t) pack + x(t+1) load
                const int j = lane & 31, bbl = lane >> 5, px = (w - 14) * 32 + j;
                hflat[p][bbl][px] = pack2(xf.x, xf.y);
                if (!last)
                    xf = *(const float2*)(x + ((size_t)(b0 + bbl) * T_STEPS + (t + 1)) * 128 + 2 * px);
            }
        }

        float nznext = 0.f;
        if (!last && isRed)
            nznext = noise[(((size_t)(b0 + bbr) * T_STEPS + (t + 1)) * 2 + LAYER) * 512 + rgl];

        bar_lgkm();                                       // bar_s: hflat[p] sealed

        // ---- MFMA dots: B shared across RT row-tiles ----
        {
            uint4 Bfr[KT];
            const unsigned* hbase = &hflat[p][colm & 1][kcv * KCP + kg * 4];
#pragma unroll
            for (int ktl = 0; ktl < KT; ++ktl)
                Bfr[ktl] = *(const uint4*)&hbase[ktl * 16];
#pragma unroll
            for (int j = 0; j < RT; ++j) {
                f32x4 C = {0.f, 0.f, 0.f, 0.f};
#pragma unroll
                for (int ktl = 0; ktl < KT; ++ktl)
                    C = mfma16(wfr[j * KT + ktl], Bfr[ktl], C);
                if (colm < 2)
                    *(f32x4*)&psum[p][kcv][colm][(rg * RT + j) * 16 + 4 * kg] = C;
            }
        }

        bar_lgkm();                                       // bar_b: psum ready

        // ---- reduce + tanh + post + own write into hflat[p^1] ----
        if (isRed) {
            float sum = 0.f;
#pragma unroll
            for (int c2 = 0; c2 < KC; ++c2) sum += psum[p][c2][bbr][rw];
            float h = fast_tanh(sum + cb + nz);
            float hnb = __shfl_down(h, 1);
            if ((L & 1) == 0) {
                unsigned pv = pack2(h, hnb);
                int pr = s * 64 + (rw >> 1);
                unsigned long long atom =
                    ((unsigned long long)(tagbase + (unsigned)t + 1) << 32) |
                    (unsigned long long)pv;
                if constexpr (LAYER == 0) {
                    if (t - known > THR_LEAD) {           // ring-overwrite throttle
                        __builtin_amdgcn_s_setprio(0);
                        while (t - known > THR_LEAD && budget > 0) {
                            known = __hip_atomic_load(&prog[pair], __ATOMIC_RELAXED,
                                                      __HIP_MEMORY_SCOPE_AGENT);
                            --budget;
                        }
                        __builtin_amdgcn_s_setprio(1);
                    }
                    __hip_atomic_store(&hb0[((size_t)(t & (DRING - 1)) * NBATCH + (b0 + bbr)) * 256 + pr],
                                       atom, __ATOMIC_RELAXED, __HIP_MEMORY_SCOPE_AGENT);
                } else {
                    __hip_atomic_store(&hb1[((size_t)(t & 3) * NBATCH + (b0 + bbr)) * 256 + pr],
                                       atom, __ATOMIC_RELAXED, __HIP_MEMORY_SCOPE_AGENT);
                }
                hflat[p ^ 1][bbr][OWNB + s * 64 + (rw >> 1)] = pv;
            }
            nz = nznext;
        }
        if constexpr (LAYER == 1) {                       // consumer progress
            if (s == 0 && L == 960 && t > 1)
                __hip_atomic_store(&prog[pair], t - 2, __ATOMIC_RELAXED,
                                   __HIP_MEMORY_SCOPE_AGENT);
        }
        __builtin_amdgcn_s_setprio(0);

        // ---- bottom: issue remote prefetch for t+1 ----
        if (!last) {
            if constexpr (LAYER == 1) {
                if (w >= 10) {
                    const int j = lane & 31, bbl = lane >> 5;
                    int m = (w - 10) * 32 + j;
                    int p2 = (m < s * 64) ? m : m + 64;
                    pfR = __hip_atomic_load(&hb1[((size_t)(t & 3) * NBATCH + (b0 + bbl)) * 256 + p2],
                                            __ATOMIC_RELAXED, __HIP_MEMORY_SCOPE_AGENT);
                }
            } else {
                if (w >= 8 && w < 14) {
                    int idx = (w - 8) * 64 + lane;
                    int bbl = (idx >= 192) ? 1 : 0;
                    int m = idx - bbl * 192;
                    int p2 = (m < s * 64) ? m : m + 64;
                    pfR = __hip_atomic_load(&hb0[((size_t)(t & (DRING - 1)) * NBATCH +
                                                  (b0 + bbl)) * 256 + p2],
                                            __ATOMIC_RELAXED, __HIP_MEMORY_SCOPE_AGENT);
                }
            }
        }
    }

    // ---- FC epilogue: out = h1(T-1) @ fc_w^T + fc_b (L1 s==0 WGs) ----
    if constexpr (LAYER == 1) {
        if (s == 0) {
            __shared__ float hs[2][512];
            __shared__ float part[2][512];
            if (L < 512) {
                int bl = L >> 8, pr = L & 255;
                unsigned v = poll1(&hb1[((size_t)((T_STEPS - 1) & 3) * NBATCH + (b0 + bl)) * 256 + pr],
                                   tagbase + (unsigned)T_STEPS, budget);
                half2v h2 = __builtin_bit_cast(half2v, v);
                hs[bl][2 * pr] = (float)h2.x; hs[bl][2 * pr + 1] = (float)h2.y;
            }
            __syncthreads();
            {
                int bl = L >> 9, rest = L & 511, o = rest & 31, seg = rest >> 5;
                const float* wr = fcw + o * 512 + seg * 32;
                const float* hr = &hs[bl][seg * 32];
                float a = 0.f;
#pragma unroll
                for (int k = 0; k < 32; ++k) a = fmaf(wr[k], hr[k], a);
                part[bl][rest] = a;
            }
            __syncthreads();
            if (L < 64) {
                int bl = L >> 5, o = L & 31;
                float ssum = fcb[o];
#pragma unroll
                for (int sgi = 0; sgi < 16; ++sgi) ssum += part[bl][sgi * 32 + o];
                out[(b0 + bl) * 32 + o] = ssum;
            }
        }
    }
}

__global__ __launch_bounds__(1024, 4)
void rnn_dual(const float* __restrict__ x, const float* __restrict__ noise,
              const uint4* __restrict__ wp0, const uint4* __restrict__ wp1,
              const float* __restrict__ bih0, const float* __restrict__ bhh0,
              const float* __restrict__ bih1, const float* __restrict__ bhh1,
              const float* __restrict__ fcw, const float* __restrict__ fcb,
              unsigned long long* __restrict__ hb0,
              unsigned long long* __restrict__ hb1,
              int* __restrict__ prog,
              float* __restrict__ out) {
    const int L = threadIdx.x;
    const int gid = blockIdx.x;
    const int cl = gid & 63;             // cluster: layer*32 + pair
    const int s = gid >> 6;              // sibling quarter 0..3
    const int layer = cl >> 5;
    const int pair = cl & 31;
    const int b0 = pair * 2;             // gid%8 == cl%8: co-XCD (locality only)
    if (layer == 0)
        run_layer<0>(b0, s, L, pair, x, noise, wp0, bih0, bhh0,
                     hb0, hb1, prog, nullptr, nullptr, nullptr);
    else
        run_layer<1>(b0, s, L, pair, x, noise, wp1, bih1, bhh1,
                     hb0, hb1, prog, fcw, fcb, out);
}

extern "C" void kernel_launch(void* const* d_in, const int* in_sizes, int n_in,
                              void* d_out, int out_size, void* d_ws, size_t ws_size,
                              hipStream_t stream) {
    const float* x     = (const float*)d_in[0];
    const float* noise = (const float*)d_in[1];
    const float* Wih0  = (const float*)d_in[2];
    const float* Wih1  = (const float*)d_in[3];
    const float* Whh0  = (const float*)d_in[4];
    const float* Whh1  = (const float*)d_in[5];
    const float* bih0  = (const float*)d_in[6];
    const float* bih1  = (const float*)d_in[7];
    const float* bhh0  = (const float*)d_in[8];
    const float* bhh1  = (const float*)d_in[9];
    const float* fcw   = (const float*)d_in[10];
    const float* fcb   = (const float*)d_in[11];
    float* out = (float*)d_out;

    char* ws = (char*)d_ws;
    size_t o = 0;
    uint4* wp0 = (uint4*)(ws + o); o += (size_t)NWPF * 16;      // 1 MB
    uint4* wp1 = (uint4*)(ws + o); o += (size_t)NWPF * 16;      // 1 MB
    unsigned long long* hb0 = (unsigned long long*)(ws + o);
    o += (size_t)DRING * NBATCH * 256 * 8;                      // 33.5 MB ring
    unsigned long long* hb1 = (unsigned long long*)(ws + o);
    o += (size_t)4 * NBATCH * 256 * 8;                          // 512 KB ring
    int* prog = (int*)(ws + o); o += 33 * sizeof(int);          // prog + epoch

    const int total = 2 * NWPF;
    init_pack<<<(total + 255) / 256, 256, 0, stream>>>(Wih0, Whh0, Wih1, Whh1,
                                                       wp0, wp1, prog);
    rnn_dual<<<256, 1024, 0, stream>>>(x, noise, wp0, wp1, bih0, bhh0, bih1, bhh1,
                                       fcw, fcb, hb0, hb1, prog, out);
}